// Round 5
// baseline (528.617 us; speedup 1.0000x reference)
//
#include <hip/hip_runtime.h>
#include <stdint.h>

typedef short short8 __attribute__((ext_vector_type(8)));
typedef float f32x4 __attribute__((ext_vector_type(4)));

__device__ __forceinline__ float bf2f(unsigned short u) {
  union { unsigned int i; float f; } v; v.i = ((unsigned int)u) << 16; return v.f;
}
__device__ __forceinline__ unsigned short f2bf(float f) {
  union { float f; unsigned int i; } v; v.f = f;
  unsigned int i = v.i + 0x7fffu + ((v.i >> 16) & 1u);
  return (unsigned short)(i >> 16);
}

// ---------------------------------------------------------------------------
// W fp32 -> bf16 prep: Wall = [wth | wph | wg], each 256x256 row-major [o][i]
// ---------------------------------------------------------------------------
__global__ __launch_bounds__(256) void wprep_kernel(
    const float* __restrict__ wth, const float* __restrict__ wph,
    const float* __restrict__ wg, unsigned short* __restrict__ Wall)
{
  int i = blockIdx.x * 256 + threadIdx.x;  // 768 blocks * 256 = 196608
  const float* src = (i < 65536) ? wth : ((i < 131072) ? wph : wg);
  Wall[i] = f2bf(src[i & 65535]);
}

// ---------------------------------------------------------------------------
// MFMA projections: theta -> Q[b][n][o], phi -> KT[b][n][o], g -> VT[b][o][n]
// ---------------------------------------------------------------------------
__global__ __launch_bounds__(256) void proj_kernel(
    const float* __restrict__ x, const unsigned short* __restrict__ Wall,
    const float* __restrict__ bth, const float* __restrict__ bph,
    const float* __restrict__ bg,
    unsigned short* __restrict__ Q,
    unsigned short* __restrict__ KT,
    unsigned short* __restrict__ VT)
{
  const int nt = blockIdx.x & 63, b = blockIdx.x >> 6;
  const int t = threadIdx.x, tn = t & 63, to = t >> 6;
  const int lane = t & 63, lrow = lane & 15, lgrp = lane >> 4;
  const int n0 = nt * 64;

  __shared__ __align__(16) unsigned short Xs[64][264]; // [n][i], row 528B

  const float* xb = x + (size_t)b * (1u << 20);
  #pragma unroll 4
  for (int ii = 0; ii < 64; ++ii) {
    int i = to * 64 + ii;
    Xs[tn][i] = f2bf(xb[(size_t)i * 4096 + n0 + tn]);
  }
  __syncthreads();

  short8 af[8];
  #pragma unroll
  for (int kc = 0; kc < 8; ++kc)
    af[kc] = *(const short8*)&Xs[to * 16 + lrow][kc * 32 + lgrp * 8];

  const float* Bp[3] = { bth, bph, bg };
  const int nrow0 = n0 + to * 16 + lgrp * 4;   // first of 4 output rows

  #pragma unroll
  for (int p = 0; p < 3; ++p) {
    const unsigned short* Wp = Wall + (size_t)p * 65536;
    const float* bias = Bp[p];
    for (int osc = 0; osc < 16; ++osc) {
      const int o = osc * 16 + lrow;           // this lane's output column
      short8 bf[8];
      #pragma unroll
      for (int kc = 0; kc < 8; ++kc)
        bf[kc] = *(const short8*)(Wp + (size_t)o * 256 + kc * 32 + lgrp * 8);
      f32x4 acc = { 0.f, 0.f, 0.f, 0.f };
      #pragma unroll
      for (int kc = 0; kc < 8; ++kc)
        acc = __builtin_amdgcn_mfma_f32_16x16x32_bf16(af[kc], bf[kc], acc, 0, 0, 0);
      const float bo = bias[o];
      if (p == 0) {
        unsigned short* dst = Q + ((size_t)b * 4096 + nrow0) * 256 + o;
        #pragma unroll
        for (int r = 0; r < 4; ++r) dst[r * 256] = f2bf(acc[r] + bo);
      } else if (p == 1) {
        unsigned short* dst = KT + ((size_t)b * 4096 + nrow0) * 256 + o;
        #pragma unroll
        for (int r = 0; r < 4; ++r) dst[r * 256] = f2bf(acc[r] + bo);
      } else {
        unsigned short pk[4];
        #pragma unroll
        for (int r = 0; r < 4; ++r) pk[r] = f2bf(acc[r] + bo);
        unsigned short* dst = VT + ((size_t)b * 256 + o) * 4096 + nrow0;
        *(uint2*)dst = *(const uint2*)pk;      // 4 consecutive n, 8B store
      }
    }
  }
}

// ---------------------------------------------------------------------------
// Flash attention, KV-split x4. Round-3 structure (K+V staged in LDS,
// 2 barriers/tile) + T14 async-stage split (issue t+1 global loads before
// compute of t; LDS writes after the post-compute barrier) + ones-column
// MFMA for the softmax denominator (no sum shuffle-reduce).
// ---------------------------------------------------------------------------
__global__ __launch_bounds__(256) void attn_kernel(
    const unsigned short* __restrict__ Q,
    const unsigned short* __restrict__ KT,
    const unsigned short* __restrict__ VT,
    unsigned short* __restrict__ Opart,
    float* __restrict__ Mpart, float* __restrict__ Lpart)
{
  const int idx = blockIdx.x;            // 256 x-blocks
  const int sp  = blockIdx.y;            // KV split 0..3
  const int b  = (idx & 7) >> 1;         // XCD-pair per batch (L2 locality)
  const int nt = ((idx >> 3) << 1) | (idx & 1);
  const int t = threadIdx.x;
  const int w = t >> 6, lane = t & 63;
  const int lrow = lane & 15, lgrp = lane >> 4;
  const int n0 = nt * 64;

  __shared__ __align__(16) unsigned short kt_s[32][264];  // [m][c], row 528B
  __shared__ __align__(16) unsigned short vt_s[256][40];  // [c][m], row 80B
  __shared__ __align__(16) unsigned short p_s[4][16][40]; // per-wave P staging

  const size_t bq = (size_t)b * 4096 * 256;
  const size_t bvo = (size_t)b * 256 * 4096;

  short8 qf[8];
  {
    const unsigned short* qrow = Q + bq + (size_t)(n0 + w * 16 + lrow) * 256 + lgrp * 8;
    #pragma unroll
    for (int kc = 0; kc < 8; ++kc) qf[kc] = *(const short8*)(qrow + kc * 32);
  }

  short8 ones;
  #pragma unroll
  for (int j = 0; j < 8; ++j) ones[j] = (short)0x3F80;  // bf16 1.0

  f32x4 acc[16];
  #pragma unroll
  for (int cs = 0; cs < 16; ++cs) { acc[cs][0] = 0.f; acc[cs][1] = 0.f; acc[cs][2] = 0.f; acc[cs][3] = 0.f; }
  f32x4 lacc = { 0.f, 0.f, 0.f, 0.f };   // softmax denominators via ones-MFMA
  float mrun[4] = { -3.0e38f, -3.0e38f, -3.0e38f, -3.0e38f };

  const int mt0 = sp * 32, mt1 = sp * 32 + 32;

  uint4 kreg[4], vreg[4];
  auto issue_loads = [&](int mt_) {
    #pragma unroll
    for (int j = 0; j < 4; ++j) {
      int ch = j * 256 + t, row = ch >> 5, sl = ch & 31;
      kreg[j] = *(const uint4*)(KT + bq + (size_t)(mt_ * 32 + row) * 256 + sl * 8);
    }
    #pragma unroll
    for (int j = 0; j < 4; ++j) {
      int ch = j * 256 + t, row = ch >> 2, mo = (ch & 3) * 8;
      vreg[j] = *(const uint4*)(VT + bvo + (size_t)row * 4096 + mt_ * 32 + mo);
    }
  };
  auto write_lds = [&]() {
    #pragma unroll
    for (int j = 0; j < 4; ++j) {
      int ch = j * 256 + t, row = ch >> 5, sl = ch & 31;
      *(uint4*)&kt_s[row][sl * 8] = kreg[j];
    }
    #pragma unroll
    for (int j = 0; j < 4; ++j) {
      int ch = j * 256 + t, row = ch >> 2, mo = (ch & 3) * 8;
      *(uint4*)&vt_s[row][mo] = vreg[j];
    }
  };

  // prologue: stage tile mt0
  issue_loads(mt0);
  write_lds();
  __syncthreads();

  for (int mt = mt0; mt < mt1; ++mt) {
    // issue next tile's loads early; latency hides under this tile's compute
    if (mt + 1 < mt1) issue_loads(mt + 1);

    // S = Q · K^T  (two 16-row m-subtiles)
    f32x4 s0 = { 0, 0, 0, 0 }, s1 = { 0, 0, 0, 0 };
    __builtin_amdgcn_s_setprio(1);
    #pragma unroll
    for (int kc = 0; kc < 8; ++kc) {
      short8 bk = *(const short8*)&kt_s[lrow][kc * 32 + lgrp * 8];
      s0 = __builtin_amdgcn_mfma_f32_16x16x32_bf16(qf[kc], bk, s0, 0, 0, 0);
    }
    #pragma unroll
    for (int kc = 0; kc < 8; ++kc) {
      short8 bk = *(const short8*)&kt_s[16 + lrow][kc * 32 + lgrp * 8];
      s1 = __builtin_amdgcn_mfma_f32_16x16x32_bf16(qf[kc], bk, s1, 0, 0, 0);
    }
    __builtin_amdgcn_s_setprio(0);

    // online softmax max (rows = lgrp*4 + r, cols across 16 lanes of group)
    float tmax[4];
    #pragma unroll
    for (int r = 0; r < 4; ++r) tmax[r] = fmaxf(s0[r], s1[r]);
    #pragma unroll
    for (int off = 1; off < 16; off <<= 1) {
      #pragma unroll
      for (int r = 0; r < 4; ++r) tmax[r] = fmaxf(tmax[r], __shfl_xor(tmax[r], off));
    }
    int need = 0;
    #pragma unroll
    for (int r = 0; r < 4; ++r) need |= (tmax[r] > mrun[r]) ? 1 : 0;
    if (__any(need)) {
      #pragma unroll
      for (int r = 0; r < 4; ++r) {
        float mn = fmaxf(mrun[r], tmax[r]);
        float sc = __expf(mrun[r] - mn);
        mrun[r] = mn;
        #pragma unroll
        for (int cs = 0; cs < 16; ++cs) acc[cs][r] *= sc;
        lacc[r] *= sc;
      }
    }
    float p0[4], p1[4];
    #pragma unroll
    for (int r = 0; r < 4; ++r) {
      p0[r] = __expf(s0[r] - mrun[r]);
      p1[r] = __expf(s1[r] - mrun[r]);
    }

    // P -> wave-private LDS (D-layout) then read back as A-fragment
    #pragma unroll
    for (int r = 0; r < 4; ++r) {
      p_s[w][lgrp * 4 + r][lrow]      = f2bf(p0[r]);
      p_s[w][lgrp * 4 + r][16 + lrow] = f2bf(p1[r]);
    }
    short8 pa = *(const short8*)&p_s[w][lrow][lgrp * 8];

    // PV from LDS + ones-column for the denominator
    __builtin_amdgcn_s_setprio(1);
    #pragma unroll
    for (int cs = 0; cs < 16; ++cs) {
      short8 bvv = *(const short8*)&vt_s[cs * 16 + lrow][lgrp * 8];
      acc[cs] = __builtin_amdgcn_mfma_f32_16x16x32_bf16(pa, bvv, acc[cs], 0, 0, 0);
    }
    lacc = __builtin_amdgcn_mfma_f32_16x16x32_bf16(pa, ones, lacc, 0, 0, 0);
    __builtin_amdgcn_s_setprio(0);

    __syncthreads();               // all waves done reading this tile's LDS
    if (mt + 1 < mt1) write_lds(); // vmcnt drains here, ~1 tile of latency hidden
    __syncthreads();               // staged data visible for next iteration
  }

  // epilogue: unnormalized partials
  const size_t po = ((size_t)sp * 4 + b) * (256 * 4096);
  #pragma unroll
  for (int cs = 0; cs < 16; ++cs) {
    const int c = cs * 16 + lrow;
    unsigned short pk[4];
    #pragma unroll
    for (int r = 0; r < 4; ++r) pk[r] = f2bf(acc[cs][r]);
    unsigned short* dst = Opart + po + (size_t)c * 4096 + n0 + w * 16 + lgrp * 4;
    *(uint2*)dst = *(const uint2*)pk;
  }
  if (lrow == 0) {
    const size_t mo = ((size_t)sp * 4 + b) * 4096 + n0 + w * 16 + lgrp * 4;
    #pragma unroll
    for (int r = 0; r < 4; ++r) {
      Mpart[mo + r] = mrun[r];
      Lpart[mo + r] = lacc[r];
    }
  }
}

// ---------------------------------------------------------------------------
// combine weights: ws[s][b][n] = exp(m_s - M) / sum_s exp(m_s - M) * l_s
// ---------------------------------------------------------------------------
__global__ __launch_bounds__(256) void wscomb_kernel(
    const float* __restrict__ Mpart, const float* __restrict__ Lpart,
    float* __restrict__ wsb)
{
  int i = blockIdx.x * 256 + threadIdx.x;  // 16384 = 4b * 4096n
  int b = i >> 12, n = i & 4095;
  float m[4], l[4];
  #pragma unroll
  for (int s = 0; s < 4; ++s) {
    m[s] = Mpart[((size_t)s * 4 + b) * 4096 + n];
    l[s] = Lpart[((size_t)s * 4 + b) * 4096 + n];
  }
  float M = fmaxf(fmaxf(m[0], m[1]), fmaxf(m[2], m[3]));
  float e[4], L = 0.f;
  #pragma unroll
  for (int s = 0; s < 4; ++s) { e[s] = __expf(m[s] - M); L += e[s] * l[s]; }
  float invL = 1.f / L;
  #pragma unroll
  for (int s = 0; s < 4; ++s)
    wsb[((size_t)s * 4 + b) * 4096 + n] = e[s] * invL;
}

// ---------------------------------------------------------------------------
// mask_feat = x + gamma * (wws · ysv + bws); ysv combined from Opart on the fly
// ---------------------------------------------------------------------------
__global__ __launch_bounds__(256) void maskfeat_kernel(
    const float* __restrict__ x, const unsigned short* __restrict__ Opart,
    const float* __restrict__ wsb,
    const float* __restrict__ wws, const float* __restrict__ bws,
    const float* __restrict__ gamma, float* __restrict__ mf)
{
  __shared__ __align__(16) unsigned short ys_s[64][258]; // [c2][pixel]
  __shared__ float ww_s[64][65];                          // [c2][c]
  const int pc = blockIdx.x, b = blockIdx.y;
  const int t = threadIdx.x;
  const int p0 = pc * 256;

  for (int i = t; i < 4096; i += 256) { int c = i >> 6, c2 = i & 63; ww_s[c2][c] = wws[i]; }

  // combine: flat ys index f = c2*16384 + p0 + t maps to YT row cc, col nn:
  // nn = (p0+t) & 4095 = (pc&15)*256 + t ; cc = c2*4 + (pc>>4)
  {
    const int nn = (pc & 15) * 256 + t;
    const int ccb = pc >> 4;
    float w0 = wsb[((size_t)0 * 4 + b) * 4096 + nn];
    float w1 = wsb[((size_t)1 * 4 + b) * 4096 + nn];
    float w2 = wsb[((size_t)2 * 4 + b) * 4096 + nn];
    float w3 = wsb[((size_t)3 * 4 + b) * 4096 + nn];
    const unsigned short* o0 = Opart + ((size_t)(0 * 4 + b) * 256) * 4096 + nn;
    const unsigned short* o1 = Opart + ((size_t)(1 * 4 + b) * 256) * 4096 + nn;
    const unsigned short* o2 = Opart + ((size_t)(2 * 4 + b) * 256) * 4096 + nn;
    const unsigned short* o3 = Opart + ((size_t)(3 * 4 + b) * 256) * 4096 + nn;
    #pragma unroll 4
    for (int k = 0; k < 64; ++k) {
      size_t off = (size_t)(k * 4 + ccb) * 4096;
      float v = w0 * bf2f(o0[off]) + w1 * bf2f(o1[off])
              + w2 * bf2f(o2[off]) + w3 * bf2f(o3[off]);
      ys_s[k][t] = f2bf(v);
    }
  }
  __syncthreads();

  const float g = gamma[0];
  const float* xb = x + (size_t)b * (1u << 20);
  for (int c = 0; c < 64; ++c) {
    float a0 = 0.f, a1 = 0.f, a2 = 0.f, a3 = 0.f;
    #pragma unroll 8
    for (int c2 = 0; c2 < 64; c2 += 4) {
      a0 += ww_s[c2][c]     * bf2f(ys_s[c2][t]);
      a1 += ww_s[c2 + 1][c] * bf2f(ys_s[c2 + 1][t]);
      a2 += ww_s[c2 + 2][c] * bf2f(ys_s[c2 + 2][t]);
      a3 += ww_s[c2 + 3][c] * bf2f(ys_s[c2 + 3][t]);
    }
    float out = xb[(size_t)c * 16384 + p0 + t] + g * (((a0 + a1) + (a2 + a3)) + bws[c]);
    mf[((size_t)b * 64 + c) * 16384 + p0 + t] = out;
  }
}

// ---------------------------------------------------------------------------
// conv m1: 3x3, 64->16, pad 1, relu
// ---------------------------------------------------------------------------
__global__ __launch_bounds__(256) void conv1_kernel(
    const float* __restrict__ mf, const float* __restrict__ wm1,
    const float* __restrict__ bm1, float* __restrict__ hid)
{
  __shared__ float w_s[9216]; // [(ic*9 + dy*3 + dx)*16 + oc]
  const int b = blockIdx.y, t = threadIdx.x;
  for (int i = t; i < 9216; i += 256) {
    int oc = i / 576, rem = i % 576;
    w_s[rem * 16 + oc] = wm1[i];
  }
  __syncthreads();
  const int py = blockIdx.x * 2 + (t >> 7), px = t & 127;
  float acc[16];
  #pragma unroll
  for (int oc = 0; oc < 16; ++oc) acc[oc] = bm1[oc];
  const float* mfb = mf + (size_t)b * (1u << 20);
  for (int ic = 0; ic < 64; ++ic) {
    const float* ch = mfb + ic * 16384;
    #pragma unroll
    for (int dy = 0; dy < 3; ++dy) {
      int yy = py + dy - 1;
      bool yok = (yy >= 0) && (yy < 128);
      const float* row = ch + yy * 128;
      float v0 = (yok && px > 0)   ? row[px - 1] : 0.f;
      float v1 = yok               ? row[px]     : 0.f;
      float v2 = (yok && px < 127) ? row[px + 1] : 0.f;
      const float* wr = &w_s[(ic * 9 + dy * 3) * 16];
      #pragma unroll
      for (int oc = 0; oc < 16; ++oc) acc[oc] += wr[oc] * v0;
      #pragma unroll
      for (int oc = 0; oc < 16; ++oc) acc[oc] += wr[16 + oc] * v1;
      #pragma unroll
      for (int oc = 0; oc < 16; ++oc) acc[oc] += wr[32 + oc] * v2;
    }
  }
  const size_t pix = (size_t)py * 128 + px;
  #pragma unroll
  for (int oc = 0; oc < 16; ++oc)
    hid[((size_t)b * 16 + oc) * 16384 + pix] = fmaxf(acc[oc], 0.f);
}

// ---------------------------------------------------------------------------
// conv m2: 3x3, 16->1, pad 1, sigmoid
// ---------------------------------------------------------------------------
__global__ __launch_bounds__(256) void conv2_kernel(
    const float* __restrict__ hid, const float* __restrict__ wm2,
    const float* __restrict__ bm2, float* __restrict__ mb)
{
  const int b = blockIdx.y, t = threadIdx.x;
  const int py = blockIdx.x * 2 + (t >> 7), px = t & 127;
  float acc = bm2[0];
  const float* hb = hid + (size_t)b * 16 * 16384;
  for (int ic = 0; ic < 16; ++ic) {
    const float* ch = hb + ic * 16384;
    #pragma unroll
    for (int dy = 0; dy < 3; ++dy) {
      int yy = py + dy - 1;
      bool yok = (yy >= 0) && (yy < 128);
      const float* row = ch + yy * 128;
      float v0 = (yok && px > 0)   ? row[px - 1] : 0.f;
      float v1 = yok               ? row[px]     : 0.f;
      float v2 = (yok && px < 127) ? row[px + 1] : 0.f;
      const float* wr = wm2 + (ic * 3 + dy) * 3;
      acc += wr[0] * v0 + wr[1] * v1 + wr[2] * v2;
    }
  }
  mb[(size_t)b * 16384 + py * 128 + px] = 1.f / (1.f + expf(-acc));
}

// ---------------------------------------------------------------------------
// partial convs (stride 2, no padding). pconv1 input = img * mask (fused).
// ---------------------------------------------------------------------------
__global__ __launch_bounds__(256) void pconv1_kernel(
    const float* __restrict__ img, const float* __restrict__ mb,
    const float* __restrict__ wp1, const float* __restrict__ bp1,
    float* __restrict__ xo1, float* __restrict__ m1)
{
  int i = blockIdx.x * 256 + threadIdx.x;
  if (i >= 4 * 3 * 63 * 63) return;
  int ox = i % 63, r1 = i / 63;
  int oy = r1 % 63, r2 = r1 / 63;
  int oc = r2 % 3, b = r2 / 3;
  const float* mbb = mb + (size_t)b * 16384;
  float msum = 0.f, conv = 0.f;
  for (int dy = 0; dy < 3; ++dy)
    for (int dx = 0; dx < 3; ++dx) {
      int iy = oy * 2 + dy, ix = ox * 2 + dx;
      float m = mbb[iy * 128 + ix];
      msum += m;
      for (int ic = 0; ic < 3; ++ic) {
        float v = img[((size_t)(b * 3 + ic)) * 16384 + iy * 128 + ix];
        conv += wp1[((oc * 3 + ic) * 3 + dy) * 3 + dx] * v * m;
      }
    }
  msum *= 3.f;
  bool hole = (msum == 0.f);
  xo1[i] = hole ? 0.f : (conv / msum + bp1[oc]);
  if (oc == 0) m1[(size_t)(b * 63 + oy) * 63 + ox] = hole ? 0.f : 1.f;
}

__global__ __launch_bounds__(256) void pconv2_kernel(
    const float* __restrict__ xo1, const float* __restrict__ m1,
    const float* __restrict__ wp2, const float* __restrict__ bp2,
    float* __restrict__ xo2, float* __restrict__ m2)
{
  int i = blockIdx.x * 256 + threadIdx.x;
  if (i >= 4 * 3 * 31 * 31) return;
  int ox = i % 31, r1 = i / 31;
  int oy = r1 % 31, r2 = r1 / 31;
  int oc = r2 % 3, b = r2 / 3;
  const float* m1b = m1 + (size_t)b * 3969;
  float msum = 0.f, conv = 0.f;
  for (int dy = 0; dy < 3; ++dy)
    for (int dx = 0; dx < 3; ++dx) {
      int iy = oy * 2 + dy, ix = ox * 2 + dx;
      float m = m1b[iy * 63 + ix];
      msum += m;
      for (int ic = 0; ic < 3; ++ic) {
        float v = xo1[((size_t)(b * 3 + ic)) * 3969 + iy * 63 + ix];
        conv += wp2[((oc * 3 + ic) * 3 + dy) * 3 + dx] * v;
      }
    }
  msum *= 3.f;
  bool hole = (msum == 0.f);
  xo2[i] = hole ? 0.f : (conv / msum + bp2[oc]);
  if (oc == 0) m2[(size_t)(b * 31 + oy) * 31 + ox] = hole ? 0.f : 1.f;
}

__global__ __launch_bounds__(256) void pconv3_kernel(
    const float* __restrict__ xo2, const float* __restrict__ m2,
    const float* __restrict__ wp3, const float* __restrict__ bp3,
    float* __restrict__ xo)
{
  int i = blockIdx.x * 256 + threadIdx.x;
  if (i >= 4 * 15 * 15) return;
  int ox = i % 15, r1 = i / 15;
  int oy = r1 % 15, b = r1 / 15;
  const float* m2b = m2 + (size_t)b * 961;
  float msum = 0.f, conv = 0.f;
  for (int dy = 0; dy < 3; ++dy)
    for (int dx = 0; dx < 3; ++dx) {
      int iy = oy * 2 + dy, ix = ox * 2 + dx;
      float m = m2b[iy * 31 + ix];
      msum += m;
      for (int ic = 0; ic < 3; ++ic)
        conv += wp3[(ic * 3 + dy) * 3 + dx] * xo2[((size_t)(b * 3 + ic)) * 961 + iy * 31 + ix];
    }
  msum *= 3.f;
  bool hole = (msum == 0.f);
  xo[i] = hole ? 0.f : (conv / msum + bp3[0]);
}

// ---------------------------------------------------------------------------
extern "C" void kernel_launch(void* const* d_in, const int* in_sizes, int n_in,
                              void* d_out, int out_size, void* d_ws, size_t ws_size,
                              hipStream_t stream) {
  const float* x    = (const float*)d_in[0];
  const float* img  = (const float*)d_in[1];
  const float* wg   = (const float*)d_in[2];
  const float* bg   = (const float*)d_in[3];
  const float* wth  = (const float*)d_in[4];
  const float* bth  = (const float*)d_in[5];
  const float* wph  = (const float*)d_in[6];
  const float* bph  = (const float*)d_in[7];
  const float* wws  = (const float*)d_in[8];
  const float* bws  = (const float*)d_in[9];
  const float* gam  = (const float*)d_in[10];
  const float* wm1  = (const float*)d_in[11];
  const float* bm1  = (const float*)d_in[12];
  const float* wm2  = (const float*)d_in[13];
  const float* bm2  = (const float*)d_in[14];
  const float* wp1  = (const float*)d_in[15];
  const float* bp1  = (const float*)d_in[16];
  const float* wp2  = (const float*)d_in[17];
  const float* bp2  = (const float*)d_in[18];
  const float* wp3  = (const float*)d_in[19];
  const float* bp3  = (const float*)d_in[20];

  char* ws = (char*)d_ws;
  const size_t MB = (size_t)1 << 20;
  unsigned short* Qb    = (unsigned short*)(ws);            // 8 MB
  unsigned short* KTb   = (unsigned short*)(ws + 8 * MB);   // 8 MB
  unsigned short* VTb   = (unsigned short*)(ws + 16 * MB);  // 8 MB
  unsigned short* Opart = (unsigned short*)(ws + 24 * MB);  // 4*4*256*4096*2 = 32 MB
  float* Mpart = (float*)(ws + 56 * MB);                    // 256 KB
  float* Lpart = (float*)(ws + 56 * MB + 256 * 1024);       // 256 KB
  float* wsb   = (float*)(ws + 56 * MB + 512 * 1024);       // 256 KB
  unsigned short* Wall = (unsigned short*)(ws + 57 * MB);   // 384 KB
  // reuse Qb region after attention is done:
  float* hid = (float*)(ws);                                // 4 MB (Qb dead)
  float* xo1 = (float*)(ws + 4 * MB);
  float* m1  = xo1 + 4 * 3 * 63 * 63;
  float* xo2 = m1 + 4 * 63 * 63;
  float* m2  = xo2 + 4 * 3 * 31 * 31;

  float* out_xo = (float*)d_out;                 // (4,1,15,15) = 900
  float* out_mf = out_xo + 900;                  // (4,64,128,128)
  float* out_mb = out_mf + 4 * 64 * 128 * 128;   // (4,128,128)

  wprep_kernel<<<dim3(768), 256, 0, stream>>>(wth, wph, wg, Wall);
  proj_kernel<<<dim3(256), 256, 0, stream>>>(x, Wall, bth, bph, bg, Qb, KTb, VTb);
  attn_kernel<<<dim3(256, 4), 256, 0, stream>>>(Qb, KTb, VTb, Opart, Mpart, Lpart);
  wscomb_kernel<<<dim3(64), 256, 0, stream>>>(Mpart, Lpart, wsb);
  maskfeat_kernel<<<dim3(64, 4), 256, 0, stream>>>(x, Opart, wsb, wws, bws, gam, out_mf);
  conv1_kernel<<<dim3(64, 4), 256, 0, stream>>>(out_mf, wm1, bm1, hid);
  conv2_kernel<<<dim3(64, 4), 256, 0, stream>>>(hid, wm2, bm2, out_mb);
  pconv1_kernel<<<dim3(187), 256, 0, stream>>>(img, out_mb, wp1, bp1, xo1, m1);
  pconv2_kernel<<<dim3(46), 256, 0, stream>>>(xo1, m1, wp2, bp2, xo2, m2);
  pconv3_kernel<<<dim3(4), 256, 0, stream>>>(xo2, m2, wp3, bp3, out_xo);
}

// Round 6
// 322.250 us; speedup vs baseline: 1.6404x; 1.6404x over previous
//
#include <hip/hip_runtime.h>
#include <stdint.h>

typedef short short8 __attribute__((ext_vector_type(8)));
typedef float f32x4 __attribute__((ext_vector_type(4)));

__device__ __forceinline__ float bf2f(unsigned short u) {
  union { unsigned int i; float f; } v; v.i = ((unsigned int)u) << 16; return v.f;
}
__device__ __forceinline__ unsigned short f2bf(float f) {
  union { float f; unsigned int i; } v; v.f = f;
  unsigned int i = v.i + 0x7fffu + ((v.i >> 16) & 1u);
  return (unsigned short)(i >> 16);
}

// ---------------------------------------------------------------------------
// W fp32 -> bf16 prep: Wall = [wth | wph | wg], each 256x256 row-major [o][i]
// ---------------------------------------------------------------------------
__global__ __launch_bounds__(256) void wprep_kernel(
    const float* __restrict__ wth, const float* __restrict__ wph,
    const float* __restrict__ wg, unsigned short* __restrict__ Wall)
{
  int i = blockIdx.x * 256 + threadIdx.x;  // 768 blocks * 256 = 196608
  const float* src = (i < 65536) ? wth : ((i < 131072) ? wph : wg);
  Wall[i] = f2bf(src[i & 65535]);
}

// ---------------------------------------------------------------------------
// MFMA projections: theta -> Q[b][n][o], phi -> KT[b][n][o], g -> VT[b][o][n]
// o-range split x4 across blockIdx.y for occupancy (4 blocks/CU).
// ---------------------------------------------------------------------------
__global__ __launch_bounds__(256) void proj_kernel(
    const float* __restrict__ x, const unsigned short* __restrict__ Wall,
    const float* __restrict__ bth, const float* __restrict__ bph,
    const float* __restrict__ bg,
    unsigned short* __restrict__ Q,
    unsigned short* __restrict__ KT,
    unsigned short* __restrict__ VT)
{
  const int nt = blockIdx.x, og = blockIdx.y, b = blockIdx.z;
  const int t = threadIdx.x, tn = t & 63, to = t >> 6;
  const int lane = t & 63, lrow = lane & 15, lgrp = lane >> 4;
  const int n0 = nt * 64;

  __shared__ __align__(16) unsigned short Xs[64][264]; // [n][i], row 528B

  const float* xb = x + (size_t)b * (1u << 20);
  #pragma unroll 4
  for (int ii = 0; ii < 64; ++ii) {
    int i = to * 64 + ii;
    Xs[tn][i] = f2bf(xb[(size_t)i * 4096 + n0 + tn]);
  }
  __syncthreads();

  short8 af[8];
  #pragma unroll
  for (int kc = 0; kc < 8; ++kc)
    af[kc] = *(const short8*)&Xs[to * 16 + lrow][kc * 32 + lgrp * 8];

  const float* Bp[3] = { bth, bph, bg };
  const int nrow0 = n0 + to * 16 + lgrp * 4;   // first of 4 output rows

  #pragma unroll
  for (int p = 0; p < 3; ++p) {
    const unsigned short* Wp = Wall + (size_t)p * 65536;
    const float* bias = Bp[p];
    for (int osc = og * 4; osc < og * 4 + 4; ++osc) {
      const int o = osc * 16 + lrow;           // this lane's output column
      short8 bf[8];
      #pragma unroll
      for (int kc = 0; kc < 8; ++kc)
        bf[kc] = *(const short8*)(Wp + (size_t)o * 256 + kc * 32 + lgrp * 8);
      f32x4 acc = { 0.f, 0.f, 0.f, 0.f };
      #pragma unroll
      for (int kc = 0; kc < 8; ++kc)
        acc = __builtin_amdgcn_mfma_f32_16x16x32_bf16(af[kc], bf[kc], acc, 0, 0, 0);
      const float bo = bias[o];
      if (p == 0) {
        unsigned short* dst = Q + ((size_t)b * 4096 + nrow0) * 256 + o;
        #pragma unroll
        for (int r = 0; r < 4; ++r) dst[r * 256] = f2bf(acc[r] + bo);
      } else if (p == 1) {
        unsigned short* dst = KT + ((size_t)b * 4096 + nrow0) * 256 + o;
        #pragma unroll
        for (int r = 0; r < 4; ++r) dst[r * 256] = f2bf(acc[r] + bo);
      } else {
        unsigned short pk[4];
        #pragma unroll
        for (int r = 0; r < 4; ++r) pk[r] = f2bf(acc[r] + bo);
        unsigned short* dst = VT + ((size_t)b * 256 + o) * 4096 + nrow0;
        *(uint2*)dst = *(const uint2*)pk;      // 4 consecutive n, 8B store
      }
    }
  }
}

// ---------------------------------------------------------------------------
// Flash attention, KV-split x4 (round-3 structure: K+V cooperatively staged,
// 2 barriers/tile) + ones-MFMA denominator + defer-max(THR=8) + setprio.
// ---------------------------------------------------------------------------
__global__ __launch_bounds__(256) void attn_kernel(
    const unsigned short* __restrict__ Q,
    const unsigned short* __restrict__ KT,
    const unsigned short* __restrict__ VT,
    unsigned short* __restrict__ Opart,
    float* __restrict__ Mpart, float* __restrict__ Lpart)
{
  const int idx = blockIdx.x;            // 256 x-blocks
  const int sp  = blockIdx.y;            // KV split 0..3
  const int b  = (idx & 7) >> 1;         // XCD-pair per batch (L2 locality)
  const int nt = ((idx >> 3) << 1) | (idx & 1);
  const int t = threadIdx.x;
  const int w = t >> 6, lane = t & 63;
  const int lrow = lane & 15, lgrp = lane >> 4;
  const int n0 = nt * 64;

  __shared__ __align__(16) unsigned short kt_s[32][264];  // [m][c], row 528B
  __shared__ __align__(16) unsigned short vt_s[256][40];  // [c][m], row 80B
  __shared__ __align__(16) unsigned short p_s[4][16][40]; // per-wave P staging

  const size_t bq = (size_t)b * 4096 * 256;
  const size_t bvo = (size_t)b * 256 * 4096;

  short8 qf[8];
  {
    const unsigned short* qrow = Q + bq + (size_t)(n0 + w * 16 + lrow) * 256 + lgrp * 8;
    #pragma unroll
    for (int kc = 0; kc < 8; ++kc) qf[kc] = *(const short8*)(qrow + kc * 32);
  }

  short8 ones;
  #pragma unroll
  for (int j = 0; j < 8; ++j) ones[j] = (short)0x3F80;  // bf16 1.0

  f32x4 acc[16];
  #pragma unroll
  for (int cs = 0; cs < 16; ++cs) { acc[cs][0] = 0.f; acc[cs][1] = 0.f; acc[cs][2] = 0.f; acc[cs][3] = 0.f; }
  f32x4 lacc = { 0.f, 0.f, 0.f, 0.f };   // softmax denominators via ones-MFMA
  float mrun[4] = { -3.0e38f, -3.0e38f, -3.0e38f, -3.0e38f };

  for (int mt = sp * 32; mt < sp * 32 + 32; ++mt) {
    const int m0 = mt * 32;
    __syncthreads();
    // stage KT tile (32 x 256) and VT tile (256 x 32)
    {
      const uint4* src = (const uint4*)(KT + bq + (size_t)m0 * 256);
      #pragma unroll
      for (int j = 0; j < 4; ++j) {
        int ch = t + j * 256;
        int row = ch >> 5, c16 = ch & 31;
        *(uint4*)&kt_s[row][c16 * 8] = src[row * 32 + c16];
      }
      const unsigned short* vsrc = VT + bvo + m0;
      #pragma unroll
      for (int j = 0; j < 4; ++j) {
        int ch = t + j * 256;
        int row = ch >> 2, mo = (ch & 3) * 8;
        *(uint4*)&vt_s[row][mo] = *(const uint4*)(vsrc + (size_t)row * 4096 + mo);
      }
    }
    __syncthreads();

    // S = Q · K^T  (two 16-row m-subtiles)
    f32x4 s0 = { 0, 0, 0, 0 }, s1 = { 0, 0, 0, 0 };
    __builtin_amdgcn_s_setprio(1);
    #pragma unroll
    for (int kc = 0; kc < 8; ++kc) {
      short8 bk = *(const short8*)&kt_s[lrow][kc * 32 + lgrp * 8];
      s0 = __builtin_amdgcn_mfma_f32_16x16x32_bf16(qf[kc], bk, s0, 0, 0, 0);
    }
    #pragma unroll
    for (int kc = 0; kc < 8; ++kc) {
      short8 bk = *(const short8*)&kt_s[16 + lrow][kc * 32 + lgrp * 8];
      s1 = __builtin_amdgcn_mfma_f32_16x16x32_bf16(qf[kc], bk, s1, 0, 0, 0);
    }
    __builtin_amdgcn_s_setprio(0);

    // online softmax max (rows = lgrp*4 + r, cols across 16 lanes of group)
    float tmax[4];
    #pragma unroll
    for (int r = 0; r < 4; ++r) tmax[r] = fmaxf(s0[r], s1[r]);
    #pragma unroll
    for (int off = 1; off < 16; off <<= 1) {
      #pragma unroll
      for (int r = 0; r < 4; ++r) tmax[r] = fmaxf(tmax[r], __shfl_xor(tmax[r], off));
    }
    // defer-max: only rescale when the max grew by more than THR=8
    int need = 0;
    #pragma unroll
    for (int r = 0; r < 4; ++r) need |= (tmax[r] > mrun[r] + 8.f) ? 1 : 0;
    if (__any(need)) {
      #pragma unroll
      for (int r = 0; r < 4; ++r) {
        float mn = fmaxf(mrun[r], tmax[r]);
        float sc = __expf(mrun[r] - mn);
        mrun[r] = mn;
        #pragma unroll
        for (int cs = 0; cs < 16; ++cs) acc[cs][r] *= sc;
        lacc[r] *= sc;
      }
    }
    float p0[4], p1[4];
    #pragma unroll
    for (int r = 0; r < 4; ++r) {
      p0[r] = __expf(s0[r] - mrun[r]);   // bounded by e^8
      p1[r] = __expf(s1[r] - mrun[r]);
    }

    // P -> wave-private LDS (D-layout) then read back as A-fragment
    #pragma unroll
    for (int r = 0; r < 4; ++r) {
      p_s[w][lgrp * 4 + r][lrow]      = f2bf(p0[r]);
      p_s[w][lgrp * 4 + r][16 + lrow] = f2bf(p1[r]);
    }
    short8 pa = *(const short8*)&p_s[w][lrow][lgrp * 8];

    // PV from LDS + ones-column for the denominator
    __builtin_amdgcn_s_setprio(1);
    #pragma unroll
    for (int cs = 0; cs < 16; ++cs) {
      short8 bvv = *(const short8*)&vt_s[cs * 16 + lrow][lgrp * 8];
      acc[cs] = __builtin_amdgcn_mfma_f32_16x16x32_bf16(pa, bvv, acc[cs], 0, 0, 0);
    }
    lacc = __builtin_amdgcn_mfma_f32_16x16x32_bf16(pa, ones, lacc, 0, 0, 0);
    __builtin_amdgcn_s_setprio(0);
  }

  // epilogue: unnormalized partials
  const size_t po = ((size_t)sp * 4 + b) * (256 * 4096);
  #pragma unroll
  for (int cs = 0; cs < 16; ++cs) {
    const int c = cs * 16 + lrow;
    unsigned short pk[4];
    #pragma unroll
    for (int r = 0; r < 4; ++r) pk[r] = f2bf(acc[cs][r]);
    unsigned short* dst = Opart + po + (size_t)c * 4096 + n0 + w * 16 + lgrp * 4;
    *(uint2*)dst = *(const uint2*)pk;
  }
  if (lrow == 0) {
    const size_t mo = ((size_t)sp * 4 + b) * 4096 + n0 + w * 16 + lgrp * 4;
    #pragma unroll
    for (int r = 0; r < 4; ++r) {
      Mpart[mo + r] = mrun[r];
      Lpart[mo + r] = lacc[r];
    }
  }
}

// ---------------------------------------------------------------------------
// combine weights: ws[s][b][n] = exp(m_s - M) / sum_s exp(m_s - M) * l_s
// ---------------------------------------------------------------------------
__global__ __launch_bounds__(256) void wscomb_kernel(
    const float* __restrict__ Mpart, const float* __restrict__ Lpart,
    float* __restrict__ wsb)
{
  int i = blockIdx.x * 256 + threadIdx.x;  // 16384 = 4b * 4096n
  int b = i >> 12, n = i & 4095;
  float m[4], l[4];
  #pragma unroll
  for (int s = 0; s < 4; ++s) {
    m[s] = Mpart[((size_t)s * 4 + b) * 4096 + n];
    l[s] = Lpart[((size_t)s * 4 + b) * 4096 + n];
  }
  float M = fmaxf(fmaxf(m[0], m[1]), fmaxf(m[2], m[3]));
  float e[4], L = 0.f;
  #pragma unroll
  for (int s = 0; s < 4; ++s) { e[s] = __expf(m[s] - M); L += e[s] * l[s]; }
  float invL = 1.f / L;
  #pragma unroll
  for (int s = 0; s < 4; ++s)
    wsb[((size_t)s * 4 + b) * 4096 + n] = e[s] * invL;
}

// ---------------------------------------------------------------------------
// mask_feat = x + gamma * (wws · ysv + bws); ysv combined from Opart on the fly.
// c-loop split x2 across blockIdx.z.
// ---------------------------------------------------------------------------
__global__ __launch_bounds__(256) void maskfeat_kernel(
    const float* __restrict__ x, const unsigned short* __restrict__ Opart,
    const float* __restrict__ wsb,
    const float* __restrict__ wws, const float* __restrict__ bws,
    const float* __restrict__ gamma, float* __restrict__ mf)
{
  __shared__ __align__(16) unsigned short ys_s[64][258]; // [c2][pixel]
  __shared__ float ww_s[64][33];                          // [c2][c-half]
  const int pc = blockIdx.x, b = blockIdx.y;
  const int ch = blockIdx.z * 32;
  const int t = threadIdx.x;
  const int p0 = pc * 256;

  for (int i = t; i < 2048; i += 256) {
    int co = i >> 6, c2 = i & 63;
    ww_s[c2][co] = wws[(ch + co) * 64 + c2];
  }

  // combine: flat ys index f = c2*16384 + p0 + t maps to YT row cc, col nn:
  // nn = (p0+t) & 4095 = (pc&15)*256 + t ; cc = c2*4 + (pc>>4)
  {
    const int nn = (pc & 15) * 256 + t;
    const int ccb = pc >> 4;
    float w0 = wsb[((size_t)0 * 4 + b) * 4096 + nn];
    float w1 = wsb[((size_t)1 * 4 + b) * 4096 + nn];
    float w2 = wsb[((size_t)2 * 4 + b) * 4096 + nn];
    float w3 = wsb[((size_t)3 * 4 + b) * 4096 + nn];
    const unsigned short* o0 = Opart + ((size_t)(0 * 4 + b) * 256) * 4096 + nn;
    const unsigned short* o1 = Opart + ((size_t)(1 * 4 + b) * 256) * 4096 + nn;
    const unsigned short* o2 = Opart + ((size_t)(2 * 4 + b) * 256) * 4096 + nn;
    const unsigned short* o3 = Opart + ((size_t)(3 * 4 + b) * 256) * 4096 + nn;
    #pragma unroll 4
    for (int k = 0; k < 64; ++k) {
      size_t off = (size_t)(k * 4 + ccb) * 4096;
      float v = w0 * bf2f(o0[off]) + w1 * bf2f(o1[off])
              + w2 * bf2f(o2[off]) + w3 * bf2f(o3[off]);
      ys_s[k][t] = f2bf(v);
    }
  }
  __syncthreads();

  const float g = gamma[0];
  const float* xb = x + (size_t)b * (1u << 20);
  for (int co = 0; co < 32; ++co) {
    const int c = ch + co;
    float a0 = 0.f, a1 = 0.f, a2 = 0.f, a3 = 0.f;
    #pragma unroll 8
    for (int c2 = 0; c2 < 64; c2 += 4) {
      a0 += ww_s[c2][co]     * bf2f(ys_s[c2][t]);
      a1 += ww_s[c2 + 1][co] * bf2f(ys_s[c2 + 1][t]);
      a2 += ww_s[c2 + 2][co] * bf2f(ys_s[c2 + 2][t]);
      a3 += ww_s[c2 + 3][co] * bf2f(ys_s[c2 + 3][t]);
    }
    float out = xb[(size_t)c * 16384 + p0 + t] + g * (((a0 + a1) + (a2 + a3)) + bws[c]);
    mf[((size_t)b * 64 + c) * 16384 + p0 + t] = out;
  }
}

// ---------------------------------------------------------------------------
// conv m1: 3x3, 64->16, pad 1, relu. oc split across half-waves (8 oc/thread).
// ---------------------------------------------------------------------------
__global__ __launch_bounds__(256) void conv1_kernel(
    const float* __restrict__ mf, const float* __restrict__ wm1,
    const float* __restrict__ bm1, float* __restrict__ hid)
{
  __shared__ float w_s[9216]; // [(ic*9 + dy*3 + dx)*16 + oc]
  const int b = blockIdx.y, t = threadIdx.x;
  for (int i = t; i < 9216; i += 256) {
    int oc = i / 576, rem = i % 576;
    w_s[rem * 16 + oc] = wm1[i];
  }
  __syncthreads();
  const int py = blockIdx.x, px = t & 127, oh = (t >> 7) * 8;
  float acc[8];
  #pragma unroll
  for (int oc = 0; oc < 8; ++oc) acc[oc] = bm1[oh + oc];
  const float* mfb = mf + (size_t)b * (1u << 20);
  for (int ic = 0; ic < 64; ++ic) {
    const float* ch = mfb + ic * 16384;
    #pragma unroll
    for (int dy = 0; dy < 3; ++dy) {
      int yy = py + dy - 1;
      bool yok = (yy >= 0) && (yy < 128);
      const float* row = ch + yy * 128;
      float v0 = (yok && px > 0)   ? row[px - 1] : 0.f;
      float v1 = yok               ? row[px]     : 0.f;
      float v2 = (yok && px < 127) ? row[px + 1] : 0.f;
      const float* wr = &w_s[(ic * 9 + dy * 3) * 16 + oh];
      #pragma unroll
      for (int oc = 0; oc < 8; ++oc) acc[oc] += wr[oc] * v0;
      #pragma unroll
      for (int oc = 0; oc < 8; ++oc) acc[oc] += wr[16 + oc] * v1;
      #pragma unroll
      for (int oc = 0; oc < 8; ++oc) acc[oc] += wr[32 + oc] * v2;
    }
  }
  const size_t pix = (size_t)py * 128 + px;
  #pragma unroll
  for (int oc = 0; oc < 8; ++oc)
    hid[((size_t)b * 16 + oh + oc) * 16384 + pix] = fmaxf(acc[oc], 0.f);
}

// ---------------------------------------------------------------------------
// conv m2: 3x3, 16->1, pad 1, sigmoid
// ---------------------------------------------------------------------------
__global__ __launch_bounds__(256) void conv2_kernel(
    const float* __restrict__ hid, const float* __restrict__ wm2,
    const float* __restrict__ bm2, float* __restrict__ mb)
{
  const int b = blockIdx.y, t = threadIdx.x;
  const int py = blockIdx.x * 2 + (t >> 7), px = t & 127;
  float acc = bm2[0];
  const float* hb = hid + (size_t)b * 16 * 16384;
  for (int ic = 0; ic < 16; ++ic) {
    const float* ch = hb + ic * 16384;
    #pragma unroll
    for (int dy = 0; dy < 3; ++dy) {
      int yy = py + dy - 1;
      bool yok = (yy >= 0) && (yy < 128);
      const float* row = ch + yy * 128;
      float v0 = (yok && px > 0)   ? row[px - 1] : 0.f;
      float v1 = yok               ? row[px]     : 0.f;
      float v2 = (yok && px < 127) ? row[px + 1] : 0.f;
      const float* wr = wm2 + (ic * 3 + dy) * 3;
      acc += wr[0] * v0 + wr[1] * v1 + wr[2] * v2;
    }
  }
  mb[(size_t)b * 16384 + py * 128 + px] = 1.f / (1.f + expf(-acc));
}

// ---------------------------------------------------------------------------
// partial convs (stride 2, no padding). pconv1 input = img * mask (fused).
// ---------------------------------------------------------------------------
__global__ __launch_bounds__(256) void pconv1_kernel(
    const float* __restrict__ img, const float* __restrict__ mb,
    const float* __restrict__ wp1, const float* __restrict__ bp1,
    float* __restrict__ xo1, float* __restrict__ m1)
{
  int i = blockIdx.x * 256 + threadIdx.x;
  if (i >= 4 * 3 * 63 * 63) return;
  int ox = i % 63, r1 = i / 63;
  int oy = r1 % 63, r2 = r1 / 63;
  int oc = r2 % 3, b = r2 / 3;
  const float* mbb = mb + (size_t)b * 16384;
  float msum = 0.f, conv = 0.f;
  for (int dy = 0; dy < 3; ++dy)
    for (int dx = 0; dx < 3; ++dx) {
      int iy = oy * 2 + dy, ix = ox * 2 + dx;
      float m = mbb[iy * 128 + ix];
      msum += m;
      for (int ic = 0; ic < 3; ++ic) {
        float v = img[((size_t)(b * 3 + ic)) * 16384 + iy * 128 + ix];
        conv += wp1[((oc * 3 + ic) * 3 + dy) * 3 + dx] * v * m;
      }
    }
  msum *= 3.f;
  bool hole = (msum == 0.f);
  xo1[i] = hole ? 0.f : (conv / msum + bp1[oc]);
  if (oc == 0) m1[(size_t)(b * 63 + oy) * 63 + ox] = hole ? 0.f : 1.f;
}

__global__ __launch_bounds__(256) void pconv2_kernel(
    const float* __restrict__ xo1, const float* __restrict__ m1,
    const float* __restrict__ wp2, const float* __restrict__ bp2,
    float* __restrict__ xo2, float* __restrict__ m2)
{
  int i = blockIdx.x * 256 + threadIdx.x;
  if (i >= 4 * 3 * 31 * 31) return;
  int ox = i % 31, r1 = i / 31;
  int oy = r1 % 31, r2 = r1 / 31;
  int oc = r2 % 3, b = r2 / 3;
  const float* m1b = m1 + (size_t)b * 3969;
  float msum = 0.f, conv = 0.f;
  for (int dy = 0; dy < 3; ++dy)
    for (int dx = 0; dx < 3; ++dx) {
      int iy = oy * 2 + dy, ix = ox * 2 + dx;
      float m = m1b[iy * 63 + ix];
      msum += m;
      for (int ic = 0; ic < 3; ++ic) {
        float v = xo1[((size_t)(b * 3 + ic)) * 3969 + iy * 63 + ix];
        conv += wp2[((oc * 3 + ic) * 3 + dy) * 3 + dx] * v;
      }
    }
  msum *= 3.f;
  bool hole = (msum == 0.f);
  xo2[i] = hole ? 0.f : (conv / msum + bp2[oc]);
  if (oc == 0) m2[(size_t)(b * 31 + oy) * 31 + ox] = hole ? 0.f : 1.f;
}

__global__ __launch_bounds__(256) void pconv3_kernel(
    const float* __restrict__ xo2, const float* __restrict__ m2,
    const float* __restrict__ wp3, const float* __restrict__ bp3,
    float* __restrict__ xo)
{
  int i = blockIdx.x * 256 + threadIdx.x;
  if (i >= 4 * 15 * 15) return;
  int ox = i % 15, r1 = i / 15;
  int oy = r1 % 15, b = r1 / 15;
  const float* m2b = m2 + (size_t)b * 961;
  float msum = 0.f, conv = 0.f;
  for (int dy = 0; dy < 3; ++dy)
    for (int dx = 0; dx < 3; ++dx) {
      int iy = oy * 2 + dy, ix = ox * 2 + dx;
      float m = m2b[iy * 31 + ix];
      msum += m;
      for (int ic = 0; ic < 3; ++ic)
        conv += wp3[(ic * 3 + dy) * 3 + dx] * xo2[((size_t)(b * 3 + ic)) * 961 + iy * 31 + ix];
    }
  msum *= 3.f;
  bool hole = (msum == 0.f);
  xo[i] = hole ? 0.f : (conv / msum + bp3[0]);
}

// ---------------------------------------------------------------------------
extern "C" void kernel_launch(void* const* d_in, const int* in_sizes, int n_in,
                              void* d_out, int out_size, void* d_ws, size_t ws_size,
                              hipStream_t stream) {
  const float* x    = (const float*)d_in[0];
  const float* img  = (const float*)d_in[1];
  const float* wg   = (const float*)d_in[2];
  const float* bg   = (const float*)d_in[3];
  const float* wth  = (const float*)d_in[4];
  const float* bth  = (const float*)d_in[5];
  const float* wph  = (const float*)d_in[6];
  const float* bph  = (const float*)d_in[7];
  const float* wws  = (const float*)d_in[8];
  const float* bws  = (const float*)d_in[9];
  const float* gam  = (const float*)d_in[10];
  const float* wm1  = (const float*)d_in[11];
  const float* bm1  = (const float*)d_in[12];
  const float* wm2  = (const float*)d_in[13];
  const float* bm2  = (const float*)d_in[14];
  const float* wp1  = (const float*)d_in[15];
  const float* bp1  = (const float*)d_in[16];
  const float* wp2  = (const float*)d_in[17];
  const float* bp2  = (const float*)d_in[18];
  const float* wp3  = (const float*)d_in[19];
  const float* bp3  = (const float*)d_in[20];

  char* ws = (char*)d_ws;
  const size_t MB = (size_t)1 << 20;
  unsigned short* Qb    = (unsigned short*)(ws);            // 8 MB
  unsigned short* KTb   = (unsigned short*)(ws + 8 * MB);   // 8 MB
  unsigned short* VTb   = (unsigned short*)(ws + 16 * MB);  // 8 MB
  unsigned short* Opart = (unsigned short*)(ws + 24 * MB);  // 4*4*256*4096*2 = 32 MB
  float* Mpart = (float*)(ws + 56 * MB);                    // 256 KB
  float* Lpart = (float*)(ws + 56 * MB + 256 * 1024);       // 256 KB
  float* wsb   = (float*)(ws + 56 * MB + 512 * 1024);       // 256 KB
  unsigned short* Wall = (unsigned short*)(ws + 57 * MB);   // 384 KB
  // reuse Qb region after attention is done:
  float* hid = (float*)(ws);                                // 4 MB (Qb dead)
  float* xo1 = (float*)(ws + 4 * MB);
  float* m1  = xo1 + 4 * 3 * 63 * 63;
  float* xo2 = m1 + 4 * 63 * 63;
  float* m2  = xo2 + 4 * 3 * 31 * 31;

  float* out_xo = (float*)d_out;                 // (4,1,15,15) = 900
  float* out_mf = out_xo + 900;                  // (4,64,128,128)
  float* out_mb = out_mf + 4 * 64 * 128 * 128;   // (4,128,128)

  wprep_kernel<<<dim3(768), 256, 0, stream>>>(wth, wph, wg, Wall);
  proj_kernel<<<dim3(64, 4, 4), 256, 0, stream>>>(x, Wall, bth, bph, bg, Qb, KTb, VTb);
  attn_kernel<<<dim3(256, 4), 256, 0, stream>>>(Qb, KTb, VTb, Opart, Mpart, Lpart);
  wscomb_kernel<<<dim3(64), 256, 0, stream>>>(Mpart, Lpart, wsb);
  maskfeat_kernel<<<dim3(64, 4, 2), 256, 0, stream>>>(x, Opart, wsb, wws, bws, gam, out_mf);
  conv1_kernel<<<dim3(128, 4), 256, 0, stream>>>(out_mf, wm1, bm1, hid);
  conv2_kernel<<<dim3(64, 4), 256, 0, stream>>>(hid, wm2, bm2, out_mb);
  pconv1_kernel<<<dim3(187), 256, 0, stream>>>(img, out_mb, wp1, bp1, xo1, m1);
  pconv2_kernel<<<dim3(46), 256, 0, stream>>>(xo1, m1, wp2, bp2, xo2, m2);
  pconv3_kernel<<<dim3(4), 256, 0, stream>>>(xo2, m2, wp3, bp3, out_xo);
}